// Round 1
// baseline (381.900 us; speedup 1.0000x reference)
//
#include <hip/hip_runtime.h>
#include <hip/hip_bf16.h>
#include <cstdint>

typedef __attribute__((ext_vector_type(8))) short short8;
typedef __attribute__((ext_vector_type(4))) float floatx4;
typedef __attribute__((ext_vector_type(16))) float floatx16;

#define NC   5
#define PP   196
#define DD   384
#define MM   512
#define ROWS (MM * PP)     /* 100352 = 1568 * 64 exactly */
#define NRB  1568
#define EPSN 1e-12f

/* unified column space: 5*196=980 real cols padded to 1024 = 16 tiles x 64 (2 ct x 32).
   cols >= 980 replicate col 979 (class 4): max-invariant duplicates.
   swizzled B: [tile 16][kk 24][ct 2][64 lanes * 16 B]  for mfma_32x32x16 B-fragments */
#define NTILES      16
#define TILE_BYTES  49152   /* 24 * 2 * 1024 */
#define KSTEP_BYTES 2048    /* one kk: both ct slices */

/* monotone float <-> uint encoding so atomicMax(unsigned) orders like float */
__device__ __forceinline__ unsigned enc_f(float f) {
    unsigned u = __float_as_uint(f);
    return (u & 0x80000000u) ? ~u : (u | 0x80000000u);
}
__device__ __forceinline__ float dec_f(unsigned u) {
    unsigned b = (u & 0x80000000u) ? (u ^ 0x80000000u) : ~u;
    return __uint_as_float(b);
}
#define ENC_NEG_INF 0x007FFFFFu

__device__ __forceinline__ int cls_of(int col) {
    return (col >= 784) ? 4 : (col >= 588) ? 3 : (col >= 392) ? 2 : (col >= 196) ? 1 : 0;
}

/* ---- pass 1a: 1/||support_row|| (980 rows) ---- */
__global__ __launch_bounds__(256) void k_norm0(const float* __restrict__ sup,
                                               float* __restrict__ sinv) {
    int wid = threadIdx.x >> 6, lane = threadIdx.x & 63;
    int r = blockIdx.x * 4 + wid;
    if (r >= NC * PP) return;
    const float* src = sup + (size_t)r * DD;
    float s = 0.f;
    #pragma unroll
    for (int j = 0; j < 6; ++j) { float v = src[lane + j * 64]; s += v * v; }
    #pragma unroll
    for (int off = 1; off < 64; off <<= 1) s += __shfl_xor(s, off, 64);
    if (lane == 0) sinv[r] = 1.0f / fmaxf(sqrtf(s), EPSN);
}

/* ---- pass 1b: normalize + swizzle support into 32x32x16 B-fragment order.
        slice s -> (tile t, kk, ct, lane); lane holds col = t*64+ct*32+(lane&31),
        k = kk*16 + (lane>>5)*8 + e (8 contiguous). support flat row == global col. ---- */
__global__ __launch_bounds__(256) void k_swz(const float* __restrict__ sup,
                                             const float* __restrict__ sinv,
                                             __hip_bfloat16* __restrict__ snw) {
    int s = blockIdx.x * 256 + threadIdx.x;       /* 49152 slices of 16 B */
    int lane = s & 63;
    int r1 = s >> 6;
    int ct = r1 & 1;
    int r2 = r1 >> 1;
    int kk = r2 % 24;
    int t  = r2 / 24;
    int col = t * 64 + ct * 32 + (lane & 31);
    if (col > NC * PP - 1) col = NC * PP - 1;      /* replicate last col: max-invariant */
    int srow = col;                                /* [c][196] concat == global col */
    const float* sp = sup + (size_t)srow * DD + kk * 16 + (lane >> 5) * 8;
    float inv = sinv[srow];
    alignas(16) __hip_bfloat16 hb[8];
    #pragma unroll
    for (int e = 0; e < 8; ++e) hb[e] = __float2bfloat16(sp[e] * inv);
    *(uint4*)((char*)snw + (size_t)s * 16) = *(const uint4*)hb;
}

/* ---- main: one block per 64-row strip; A in LDS in 32x32x16 FRAGMENT ORDER
        (conflict-free ds_read_b128); waves stream B from L2, depth-3 pipeline
        with cross-tile prefetch; NO barriers in the main loop.
        16 col-tiles of 64 -> exactly 4 per wave (perfect balance). ---- */
__global__ __launch_bounds__(256, 3) void k_gemm_max(const float* __restrict__ q,
                                                     const __hip_bfloat16* __restrict__ snw,
                                                     float* __restrict__ rowmaxg) {
    /* As fragment order: [kk 24][rt 2][lane 64][8 bf16] = 49152 B */
    __shared__ __hip_bfloat16 As[24 * 2 * 64 * 8];
    __shared__ unsigned rmax[64 * NC];
    __shared__ float rss[64];

    const int tid  = threadIdx.x;
    const int row0 = blockIdx.x * 64;
    const int lane = tid & 63;
    const int wav  = tid >> 6;

    for (int i = tid; i < 64 * NC; i += 256) rmax[i] = ENC_NEG_INF;

    /* ---- A staging: fp32 -> bf16 -> LDS fragment slots; fused row sumsq.
            Thread (arow=tid>>2, ch=asub+4i): kk=ch>>1, half=ch&1,
            lane slot = half*32 + (arow&31), rt = arow>>5.
            Non-temporal: query must not evict B from L2. */
    {
        const int arow = tid >> 2;
        const int asub = tid & 3;
        const int rt   = arow >> 5, r5 = arow & 31;
        const float* src = q + (size_t)(row0 + arow) * DD;
        float ss = 0.f;
        #pragma unroll
        for (int i = 0; i < 12; ++i) {
            int ch = asub + i * 4;
            const floatx4* p = (const floatx4*)(src + ch * 8);
            floatx4 x0 = __builtin_nontemporal_load(p);
            floatx4 x1 = __builtin_nontemporal_load(p + 1);
            ss += x0.x*x0.x + x0.y*x0.y + x0.z*x0.z + x0.w*x0.w
                + x1.x*x1.x + x1.y*x1.y + x1.z*x1.z + x1.w*x1.w;
            alignas(16) __hip_bfloat16 hb[8];
            hb[0] = __float2bfloat16(x0.x); hb[1] = __float2bfloat16(x0.y);
            hb[2] = __float2bfloat16(x0.z); hb[3] = __float2bfloat16(x0.w);
            hb[4] = __float2bfloat16(x1.x); hb[5] = __float2bfloat16(x1.y);
            hb[6] = __float2bfloat16(x1.z); hb[7] = __float2bfloat16(x1.w);
            int kk = ch >> 1, half = ch & 1;
            *(uint4*)&As[((kk * 2 + rt) * 64 + half * 32 + r5) * 8] = *(const uint4*)hb;
        }
        ss += __shfl_xor(ss, 1, 64);
        ss += __shfl_xor(ss, 2, 64);
        if (asub == 0) rss[arow] = ss;
    }

    /* B preload (kk 0..2 of this wave's first tile) overlaps the barrier */
    const char* bbase = (const char*)snw + (size_t)wav * TILE_BYTES + (size_t)lane * 16;
    short8 b0[2], b1[2], b2[2], a[2];
    #pragma unroll
    for (int ct = 0; ct < 2; ++ct) b0[ct] = ((const short8*)(bbase + 0 * KSTEP_BYTES))[ct * 64];
    #pragma unroll
    for (int ct = 0; ct < 2; ++ct) b1[ct] = ((const short8*)(bbase + 1 * KSTEP_BYTES))[ct * 64];
    #pragma unroll
    for (int ct = 0; ct < 2; ++ct) b2[ct] = ((const short8*)(bbase + 2 * KSTEP_BYTES))[ct * 64];

    __syncthreads();                            /* the ONLY barrier before the epilogue */

    #define LOAD_NEXT(buf, step)                                                     \
        do {                                                                         \
            int nk = kk + 3 + (step);                                                \
            if (nk < 24) {                                                           \
                _Pragma("unroll")                                                    \
                for (int ct = 0; ct < 2; ++ct)                                       \
                    buf[ct] = ((const short8*)(bbase + nk * KSTEP_BYTES))[ct * 64];  \
            } else if (g + 4 < NTILES) {                                             \
                _Pragma("unroll")                                                    \
                for (int ct = 0; ct < 2; ++ct)                                       \
                    buf[ct] = ((const short8*)(bbase + 4 * TILE_BYTES +              \
                                               (nk - 24) * KSTEP_BYTES))[ct * 64];   \
            }                                                                        \
        } while (0)

    #define MFMA_STEP(buf, kkoff)                                                    \
        do {                                                                         \
            _Pragma("unroll")                                                        \
            for (int rt = 0; rt < 2; ++rt)                                           \
                a[rt] = *(const short8*)&As[(((kk + (kkoff)) * 2 + rt) * 64 + lane) * 8]; \
            _Pragma("unroll")                                                        \
            for (int rt = 0; rt < 2; ++rt)                                           \
                _Pragma("unroll")                                                    \
                for (int ct = 0; ct < 2; ++ct)                                       \
                    acc[rt][ct] = __builtin_amdgcn_mfma_f32_32x32x16_bf16(           \
                        a[rt], buf[ct], acc[rt][ct], 0, 0, 0);                       \
        } while (0)

    #pragma unroll 1
    for (int g = wav; g < NTILES; g += 4) {
        floatx16 acc[2][2];
        #pragma unroll
        for (int i = 0; i < 2; ++i)
            #pragma unroll
            for (int j = 0; j < 2; ++j)
                acc[i][j] = (floatx16){0.f,0.f,0.f,0.f, 0.f,0.f,0.f,0.f,
                                       0.f,0.f,0.f,0.f, 0.f,0.f,0.f,0.f};

        #pragma unroll 1
        for (int kk = 0; kk < 24; kk += 3) {
            MFMA_STEP(b0, 0); LOAD_NEXT(b0, 0);
            MFMA_STEP(b1, 1); LOAD_NEXT(b1, 1);
            MFMA_STEP(b2, 2); LOAD_NEXT(b2, 2);
        }

        /* ---- epilogue: per-class col-max. C layout: col=lane&31,
                row = rt*32 + (reg&3) + 8*(reg>>2) + 4*(lane>>5).
                Tile may span 2 classes (boundary cuts mid-tile): mask per lane.
                Overlaps the already-issued next-tile B loads. ---- */
        {
            const int colbase = g * 64;
            int ce = colbase + 63; if (ce > NC * PP - 1) ce = NC * PP - 1;
            const int clo = cls_of(colbase), chi = cls_of(ce);
            int lcls[2];
            #pragma unroll
            for (int ct = 0; ct < 2; ++ct) {
                int col = colbase + ct * 32 + (lane & 31);
                if (col > NC * PP - 1) col = NC * PP - 1;
                lcls[ct] = cls_of(col);
            }
            const int hi = lane >> 5;
            if (clo == chi) {                      /* common case: single class */
                #pragma unroll
                for (int rt = 0; rt < 2; ++rt)
                    #pragma unroll
                    for (int reg = 0; reg < 16; ++reg) {
                        float v = fmaxf(acc[rt][0][reg], acc[rt][1][reg]);
                        #pragma unroll
                        for (int off = 1; off < 32; off <<= 1)
                            v = fmaxf(v, __shfl_xor(v, off, 64));
                        if ((lane & 31) == 0) {
                            int row = rt * 32 + (reg & 3) + 8 * (reg >> 2) + 4 * hi;
                            atomicMax(&rmax[row * NC + clo], enc_f(v));
                        }
                    }
            } else {                               /* one boundary tile per wave */
                #pragma unroll 1
                for (int cc = clo; cc <= chi; ++cc) {
                    #pragma unroll
                    for (int rt = 0; rt < 2; ++rt)
                        #pragma unroll
                        for (int reg = 0; reg < 16; ++reg) {
                            float v0 = (lcls[0] == cc) ? acc[rt][0][reg] : -INFINITY;
                            float v1 = (lcls[1] == cc) ? acc[rt][1][reg] : -INFINITY;
                            float v = fmaxf(v0, v1);
                            #pragma unroll
                            for (int off = 1; off < 32; off <<= 1)
                                v = fmaxf(v, __shfl_xor(v, off, 64));
                            if ((lane & 31) == 0) {
                                int row = rt * 32 + (reg & 3) + 8 * (reg >> 2) + 4 * hi;
                                atomicMax(&rmax[row * NC + cc], enc_f(v));
                            }
                        }
                }
            }
        }
        bbase += 4 * TILE_BYTES;
    }

    __syncthreads();
    /* rowmaxg layout [c][row] -> coalesced stores here, coalesced loads in k_top6 */
    for (int i = tid; i < 64 * NC; i += 256) {
        int c = i >> 6, row = i & 63;
        float inv = 1.0f / fmaxf(sqrtf(rss[row]), EPSN);
        __builtin_nontemporal_store(dec_f(rmax[row * NC + c]) * inv,
                                    &rowmaxg[(size_t)c * ROWS + row0 + row]);
    }
}

/* ---- top-6 sum per (m, c): one wave each ---- */
__global__ __launch_bounds__(256) void k_top6(const float* __restrict__ rowmaxg,
                                              const float* __restrict__ scale,
                                              const float* __restrict__ bias,
                                              float* __restrict__ out) {
    int wav = threadIdx.x >> 6, lane = threadIdx.x & 63;
    int pair = blockIdx.x * 4 + wav;
    if (pair >= MM * NC) return;
    int m = pair / NC, c = pair % NC;
    size_t base = (size_t)c * ROWS + (size_t)m * PP;
    float v[4];
    #pragma unroll
    for (int i = 0; i < 4; ++i) {
        int p = lane + i * 64;
        v[i] = (p < PP) ? rowmaxg[base + p] : -INFINITY;
    }
    float sum = 0.f;
    for (int t = 0; t < 6; ++t) {
        float bv = v[0]; int bi = 0;
        #pragma unroll
        for (int i = 1; i < 4; ++i) { if (v[i] > bv) { bv = v[i]; bi = i; } }
        int gid = bi * 64 + lane;
        #pragma unroll
        for (int off = 1; off < 64; off <<= 1) {
            float ov = __shfl_xor(bv, off, 64);
            int og  = __shfl_xor(gid, off, 64);
            if (ov > bv || (ov == bv && og < gid)) { bv = ov; gid = og; }
        }
        sum += bv;
        if ((gid & 63) == lane) v[gid >> 6] = -INFINITY;  /* kill exactly one */
    }
    if (lane == 0) out[pair] = scale[0] * (sum + bias[0]);
}

extern "C" void kernel_launch(void* const* d_in, const int* in_sizes, int n_in,
                              void* d_out, int out_size, void* d_ws, size_t ws_size,
                              hipStream_t stream) {
    const float* support = (const float*)d_in[0];
    const float* query   = (const float*)d_in[1];
    const float* scale   = (const float*)d_in[2];
    const float* bias    = (const float*)d_in[3];
    float* out = (float*)d_out;

    char* ws = (char*)d_ws;
    __hip_bfloat16* snw = (__hip_bfloat16*)ws;             /* 16*49152 = 786432 B */
    float* sinv         = (float*)(ws + 786432);           /* 980*4 -> pad to 4096 */
    float* rowmaxg      = (float*)(ws + 786432 + 4096);    /* 5*100352*4 = 2007040 */

    hipLaunchKernelGGL(k_norm0,   dim3(245),  dim3(256), 0, stream, support, sinv);
    hipLaunchKernelGGL(k_swz,     dim3(192),  dim3(256), 0, stream, support, sinv, snw);
    hipLaunchKernelGGL(k_gemm_max,dim3(NRB),  dim3(256), 0, stream, query, snw, rowmaxg);
    hipLaunchKernelGGL(k_top6,    dim3(640),  dim3(256), 0, stream, rowmaxg, scale, bias, out);
}

// Round 2
// 312.791 us; speedup vs baseline: 1.2209x; 1.2209x over previous
//
#include <hip/hip_runtime.h>
#include <hip/hip_bf16.h>
#include <cstdint>

typedef __attribute__((ext_vector_type(8))) short short8;
typedef __attribute__((ext_vector_type(4))) float floatx4;

#define NC   5
#define PP   196
#define DD   384
#define MM   512
#define ROWS (MM * PP)     /* 100352 = 1568 * 64 exactly */
#define NRB  1568
#define EPSN 1e-12f

/* unified column space: 5*196=980 real cols padded to 1024 = 16 tiles x 64 (4 ct x 16).
   cols >= 980 replicate col 979 (class 4): max-invariant duplicates.
   swizzled B: [tile 16][kk 12][ct 4][64 lanes * 16 B] for mfma_16x16x32 B-fragments:
   lane holds col = t*64 + ct*16 + (lane&15), k = kk*32 + (lane>>4)*8 + e */
#define NTILES      16
#define TILE_BYTES  49152   /* 12 * 4 * 1024 */
#define KSTEP_BYTES 4096

/* monotone float <-> uint encoding so atomicMax(unsigned) orders like float */
__device__ __forceinline__ unsigned enc_f(float f) {
    unsigned u = __float_as_uint(f);
    return (u & 0x80000000u) ? ~u : (u | 0x80000000u);
}
__device__ __forceinline__ float dec_f(unsigned u) {
    unsigned b = (u & 0x80000000u) ? (u ^ 0x80000000u) : ~u;
    return __uint_as_float(b);
}
#define ENC_NEG_INF 0x007FFFFFu

__device__ __forceinline__ int cls_of(int col) {
    return (col >= 784) ? 4 : (col >= 588) ? 3 : (col >= 392) ? 2 : (col >= 196) ? 1 : 0;
}

/* ---- pass 1a: 1/||support_row|| (980 rows) ---- */
__global__ __launch_bounds__(256) void k_norm0(const float* __restrict__ sup,
                                               float* __restrict__ sinv) {
    int wid = threadIdx.x >> 6, lane = threadIdx.x & 63;
    int r = blockIdx.x * 4 + wid;
    if (r >= NC * PP) return;
    const float* src = sup + (size_t)r * DD;
    float s = 0.f;
    #pragma unroll
    for (int j = 0; j < 6; ++j) { float v = src[lane + j * 64]; s += v * v; }
    #pragma unroll
    for (int off = 1; off < 64; off <<= 1) s += __shfl_xor(s, off, 64);
    if (lane == 0) sinv[r] = 1.0f / fmaxf(sqrtf(s), EPSN);
}

/* ---- pass 1b: normalize + swizzle support into MFMA B-fragment order ---- */
__global__ __launch_bounds__(256) void k_swz(const float* __restrict__ sup,
                                             const float* __restrict__ sinv,
                                             __hip_bfloat16* __restrict__ snw) {
    int s = blockIdx.x * 256 + threadIdx.x;       /* 49152 slices of 16 B */
    int lane = s & 63;
    int r1 = s >> 6;
    int ct = r1 & 3;
    int r2 = r1 >> 2;
    int kk = r2 % 12;
    int t  = r2 / 12;                              /* 0..15 global col tile */
    int c16 = lane & 15, quad = lane >> 4;
    int col = t * 64 + ct * 16 + c16;              /* global col */
    if (col > NC * PP - 1) col = NC * PP - 1;      /* replicate last col: max-invariant */
    int srow = col;                                /* [c][196] concat == global col */
    const float* sp = sup + (size_t)srow * DD + kk * 32 + quad * 8;
    float inv = sinv[srow];
    alignas(16) __hip_bfloat16 hb[8];
    #pragma unroll
    for (int e = 0; e < 8; ++e) hb[e] = __float2bfloat16(sp[e] * inv);
    *(uint4*)((char*)snw + (size_t)s * 16) = *(const uint4*)hb;
}

/* ---- main: one block per 64-row strip; A in LDS in MFMA FRAGMENT ORDER
        (conflict-free ds_read_b128); waves stream B from L2, depth-3 pipeline
        with cross-tile prefetch; NO barriers in the main loop.
        16 col-tiles of 64 -> exactly 4 per wave (perfect balance);
        16 independent accumulators keep the MFMA pipe fed (R1 lesson:
        32x32x16 with 4 accumulators is latency-bound at 16% util). ---- */
__global__ __launch_bounds__(256, 3) void k_gemm_max(const float* __restrict__ q,
                                                     const __hip_bfloat16* __restrict__ snw,
                                                     float* __restrict__ rowmaxg) {
    /* As fragment order: [kk 12][rt 4][lane 64][8 bf16] = 49152 B */
    __shared__ __hip_bfloat16 As[12 * 4 * 64 * 8];
    __shared__ unsigned rmax[64 * NC];
    __shared__ float rss[64];

    const int tid  = threadIdx.x;
    const int row0 = blockIdx.x * 64;
    const int lane = tid & 63;
    const int wav  = tid >> 6;

    for (int i = tid; i < 64 * NC; i += 256) rmax[i] = ENC_NEG_INF;

    /* ---- A staging: fp32 -> bf16 -> LDS fragment slots; fused row sumsq.
            Thread (arow=tid>>2, ch=asub+4i) produces frag (kk=ch>>2, rt=arow>>4)
            lane (ch&3)*16+(arow&15). Non-temporal: query must not evict B from L2. */
    {
        const int arow = tid >> 2;
        const int asub = tid & 3;
        const int rt   = arow >> 4, c16 = arow & 15;
        const float* src = q + (size_t)(row0 + arow) * DD;
        float ss = 0.f;
        #pragma unroll
        for (int i = 0; i < 12; ++i) {
            int ch = asub + i * 4;
            const floatx4* p = (const floatx4*)(src + ch * 8);
            floatx4 x0 = __builtin_nontemporal_load(p);
            floatx4 x1 = __builtin_nontemporal_load(p + 1);
            ss += x0.x*x0.x + x0.y*x0.y + x0.z*x0.z + x0.w*x0.w
                + x1.x*x1.x + x1.y*x1.y + x1.z*x1.z + x1.w*x1.w;
            alignas(16) __hip_bfloat16 hb[8];
            hb[0] = __float2bfloat16(x0.x); hb[1] = __float2bfloat16(x0.y);
            hb[2] = __float2bfloat16(x0.z); hb[3] = __float2bfloat16(x0.w);
            hb[4] = __float2bfloat16(x1.x); hb[5] = __float2bfloat16(x1.y);
            hb[6] = __float2bfloat16(x1.z); hb[7] = __float2bfloat16(x1.w);
            int kk = ch >> 2, quad = ch & 3;
            *(uint4*)&As[(((kk * 4 + rt) * 64) + quad * 16 + c16) * 8] = *(const uint4*)hb;
        }
        ss += __shfl_xor(ss, 1, 64);
        ss += __shfl_xor(ss, 2, 64);
        if (asub == 0) rss[arow] = ss;
    }

    /* B preload (kk 0..2 of this wave's first tile) overlaps the barrier */
    const char* bbase = (const char*)snw + (size_t)wav * TILE_BYTES + (size_t)lane * 16;
    short8 b0[4], b1[4], b2[4], a[4];
    #pragma unroll
    for (int ct = 0; ct < 4; ++ct) b0[ct] = ((const short8*)(bbase + 0 * KSTEP_BYTES))[ct * 64];
    #pragma unroll
    for (int ct = 0; ct < 4; ++ct) b1[ct] = ((const short8*)(bbase + 1 * KSTEP_BYTES))[ct * 64];
    #pragma unroll
    for (int ct = 0; ct < 4; ++ct) b2[ct] = ((const short8*)(bbase + 2 * KSTEP_BYTES))[ct * 64];

    __syncthreads();                            /* the ONLY barrier before the epilogue */

    #define LOAD_NEXT(buf, step)                                                     \
        do {                                                                         \
            int nk = kk + 3 + (step);                                                \
            if (nk < 12) {                                                           \
                _Pragma("unroll")                                                    \
                for (int ct = 0; ct < 4; ++ct)                                       \
                    buf[ct] = ((const short8*)(bbase + nk * KSTEP_BYTES))[ct * 64];  \
            } else if (g + 4 < NTILES) {                                             \
                _Pragma("unroll")                                                    \
                for (int ct = 0; ct < 4; ++ct)                                       \
                    buf[ct] = ((const short8*)(bbase + 4 * TILE_BYTES +              \
                                               (nk - 12) * KSTEP_BYTES))[ct * 64];   \
            }                                                                        \
        } while (0)

    #define MFMA_STEP(buf, kkoff)                                                    \
        do {                                                                         \
            _Pragma("unroll")                                                        \
            for (int rt = 0; rt < 4; ++rt)                                           \
                a[rt] = *(const short8*)&As[(((kk + (kkoff)) * 4 + rt) * 64 + lane) * 8]; \
            _Pragma("unroll")                                                        \
            for (int rt = 0; rt < 4; ++rt)                                           \
                _Pragma("unroll")                                                    \
                for (int ct = 0; ct < 4; ++ct)                                       \
                    acc[rt][ct] = __builtin_amdgcn_mfma_f32_16x16x32_bf16(           \
                        a[rt], buf[ct], acc[rt][ct], 0, 0, 0);                       \
        } while (0)

    #pragma unroll 1
    for (int g = wav; g < NTILES; g += 4) {
        floatx4 acc[4][4];
        #pragma unroll
        for (int i = 0; i < 4; ++i)
            #pragma unroll
            for (int j = 0; j < 4; ++j) acc[i][j] = (floatx4){0.f, 0.f, 0.f, 0.f};

        #pragma unroll 1
        for (int kk = 0; kk < 12; kk += 3) {
            MFMA_STEP(b0, 0); LOAD_NEXT(b0, 0);
            MFMA_STEP(b1, 1); LOAD_NEXT(b1, 1);
            MFMA_STEP(b2, 2); LOAD_NEXT(b2, 2);
        }

        /* ---- epilogue: per-class col-max. C layout (16x16x32):
                row = rt*16 + (lane>>4)*4 + reg, col = g*64 + ct*16 + (lane&15).
                Tile may span 2 classes (boundary cuts mid-subtile): per-lane mask.
                Each wave has exactly one boundary tile (g=3,6,9,12).
                Overlaps the already-issued next-tile B loads. ---- */
        {
            const int colbase = g * 64;
            int ce = colbase + 63; if (ce > NC * PP - 1) ce = NC * PP - 1;
            const int clo = cls_of(colbase), chi = cls_of(ce);
            const int quad = lane >> 4, c16 = lane & 15;
            if (clo == chi) {                      /* common case: single class */
                #pragma unroll
                for (int rt = 0; rt < 4; ++rt) {
                    #pragma unroll
                    for (int reg = 0; reg < 4; ++reg) {
                        float mx = fmaxf(fmaxf(acc[rt][0][reg], acc[rt][1][reg]),
                                         fmaxf(acc[rt][2][reg], acc[rt][3][reg]));
                        #pragma unroll
                        for (int off = 1; off < 16; off <<= 1)
                            mx = fmaxf(mx, __shfl_xor(mx, off, 64));
                        if (c16 == 0) {
                            int rloc = rt * 16 + quad * 4 + reg;
                            atomicMax(&rmax[rloc * NC + clo], enc_f(mx));
                        }
                    }
                }
            } else {                               /* one boundary tile per wave */
                int lcls[4];
                #pragma unroll
                for (int ct = 0; ct < 4; ++ct) {
                    int col = colbase + ct * 16 + c16;
                    if (col > NC * PP - 1) col = NC * PP - 1;
                    lcls[ct] = cls_of(col);
                }
                #pragma unroll 1
                for (int cc = clo; cc <= chi; ++cc) {
                    #pragma unroll
                    for (int rt = 0; rt < 4; ++rt) {
                        #pragma unroll
                        for (int reg = 0; reg < 4; ++reg) {
                            float mx = -INFINITY;
                            #pragma unroll
                            for (int ct = 0; ct < 4; ++ct)
                                if (lcls[ct] == cc) mx = fmaxf(mx, acc[rt][ct][reg]);
                            #pragma unroll
                            for (int off = 1; off < 16; off <<= 1)
                                mx = fmaxf(mx, __shfl_xor(mx, off, 64));
                            if (c16 == 0) {
                                int rloc = rt * 16 + quad * 4 + reg;
                                atomicMax(&rmax[rloc * NC + cc], enc_f(mx));
                            }
                        }
                    }
                }
            }
        }
        bbase += 4 * TILE_BYTES;
    }

    __syncthreads();
    /* rowmaxg layout [c][row] -> coalesced stores here, coalesced loads in k_top6 */
    for (int i = tid; i < 64 * NC; i += 256) {
        int c = i >> 6, row = i & 63;
        float inv = 1.0f / fmaxf(sqrtf(rss[row]), EPSN);
        __builtin_nontemporal_store(dec_f(rmax[row * NC + c]) * inv,
                                    &rowmaxg[(size_t)c * ROWS + row0 + row]);
    }
}

/* ---- top-6 sum per (m, c): one wave each ---- */
__global__ __launch_bounds__(256) void k_top6(const float* __restrict__ rowmaxg,
                                              const float* __restrict__ scale,
                                              const float* __restrict__ bias,
                                              float* __restrict__ out) {
    int wav = threadIdx.x >> 6, lane = threadIdx.x & 63;
    int pair = blockIdx.x * 4 + wav;
    if (pair >= MM * NC) return;
    int m = pair / NC, c = pair % NC;
    size_t base = (size_t)c * ROWS + (size_t)m * PP;
    float v[4];
    #pragma unroll
    for (int i = 0; i < 4; ++i) {
        int p = lane + i * 64;
        v[i] = (p < PP) ? rowmaxg[base + p] : -INFINITY;
    }
    float sum = 0.f;
    for (int t = 0; t < 6; ++t) {
        float bv = v[0]; int bi = 0;
        #pragma unroll
        for (int i = 1; i < 4; ++i) { if (v[i] > bv) { bv = v[i]; bi = i; } }
        int gid = bi * 64 + lane;
        #pragma unroll
        for (int off = 1; off < 64; off <<= 1) {
            float ov = __shfl_xor(bv, off, 64);
            int og  = __shfl_xor(gid, off, 64);
            if (ov > bv || (ov == bv && og < gid)) { bv = ov; gid = og; }
        }
        sum += bv;
        if ((gid & 63) == lane) v[gid >> 6] = -INFINITY;  /* kill exactly one */
    }
    if (lane == 0) out[pair] = scale[0] * (sum + bias[0]);
}

extern "C" void kernel_launch(void* const* d_in, const int* in_sizes, int n_in,
                              void* d_out, int out_size, void* d_ws, size_t ws_size,
                              hipStream_t stream) {
    const float* support = (const float*)d_in[0];
    const float* query   = (const float*)d_in[1];
    const float* scale   = (const float*)d_in[2];
    const float* bias    = (const float*)d_in[3];
    float* out = (float*)d_out;

    char* ws = (char*)d_ws;
    __hip_bfloat16* snw = (__hip_bfloat16*)ws;             /* 16*49152 = 786432 B */
    float* sinv         = (float*)(ws + 786432);           /* 980*4 -> pad to 4096 */
    float* rowmaxg      = (float*)(ws + 786432 + 4096);    /* 5*100352*4 = 2007040 */

    hipLaunchKernelGGL(k_norm0,   dim3(245),  dim3(256), 0, stream, support, sinv);
    hipLaunchKernelGGL(k_swz,     dim3(192),  dim3(256), 0, stream, support, sinv, snw);
    hipLaunchKernelGGL(k_gemm_max,dim3(NRB),  dim3(256), 0, stream, query, snw, rowmaxg);
    hipLaunchKernelGGL(k_top6,    dim3(640),  dim3(256), 0, stream, rowmaxg, scale, bias, out);
}

// Round 3
// 304.537 us; speedup vs baseline: 1.2540x; 1.0271x over previous
//
#include <hip/hip_runtime.h>
#include <hip/hip_bf16.h>
#include <cstdint>

typedef __attribute__((ext_vector_type(8))) short short8;
typedef __attribute__((ext_vector_type(4))) float floatx4;

#define NC   5
#define PP   196
#define DD   384
#define MM   512
#define ROWS (MM * PP)     /* 100352 = 3136 * 32 exactly */
#define NRB  3136          /* 32-row blocks: As=24KB -> 5-6 blocks/CU (R2: 2 blocks @48KB) */
#define BR   32            /* rows per block */
#define EPSN 1e-12f

/* unified column space: 5*196=980 real cols padded to 1024 = 16 tiles x 64 (4 ct x 16).
   cols >= 980 replicate col 979 (class 4): max-invariant duplicates.
   swizzled B: [tile 16][kk 12][ct 4][64 lanes * 16 B]; lane holds
   col = t*64 + ct*16 + (lane&15), k = kk*32 + (lane>>4)*8 + e.
   This fragment layout serves as EITHER mfma operand (A/B symmetric). */
#define NTILES      16
#define TILE_BYTES  49152   /* 12 * 4 * 1024 */
#define KSTEP_BYTES 4096

/* monotone float <-> uint encoding so atomicMax(unsigned) orders like float */
__device__ __forceinline__ unsigned enc_f(float f) {
    unsigned u = __float_as_uint(f);
    return (u & 0x80000000u) ? ~u : (u | 0x80000000u);
}
__device__ __forceinline__ float dec_f(unsigned u) {
    unsigned b = (u & 0x80000000u) ? (u ^ 0x80000000u) : ~u;
    return __uint_as_float(b);
}
#define ENC_NEG_INF 0x007FFFFFu

__device__ __forceinline__ int cls_of(int col) {
    return (col >= 784) ? 4 : (col >= 588) ? 3 : (col >= 392) ? 2 : (col >= 196) ? 1 : 0;
}

/* ---- pass 1a: 1/||support_row|| (980 rows) ---- */
__global__ __launch_bounds__(256) void k_norm0(const float* __restrict__ sup,
                                               float* __restrict__ sinv) {
    int wid = threadIdx.x >> 6, lane = threadIdx.x & 63;
    int r = blockIdx.x * 4 + wid;
    if (r >= NC * PP) return;
    const float* src = sup + (size_t)r * DD;
    float s = 0.f;
    #pragma unroll
    for (int j = 0; j < 6; ++j) { float v = src[lane + j * 64]; s += v * v; }
    #pragma unroll
    for (int off = 1; off < 64; off <<= 1) s += __shfl_xor(s, off, 64);
    if (lane == 0) sinv[r] = 1.0f / fmaxf(sqrtf(s), EPSN);
}

/* ---- pass 1b: normalize + swizzle support into MFMA fragment order ---- */
__global__ __launch_bounds__(256) void k_swz(const float* __restrict__ sup,
                                             const float* __restrict__ sinv,
                                             __hip_bfloat16* __restrict__ snw) {
    int s = blockIdx.x * 256 + threadIdx.x;       /* 49152 slices of 16 B */
    int lane = s & 63;
    int r1 = s >> 6;
    int ct = r1 & 3;
    int r2 = r1 >> 2;
    int kk = r2 % 12;
    int t  = r2 / 12;                              /* 0..15 global col tile */
    int c16 = lane & 15, quad = lane >> 4;
    int col = t * 64 + ct * 16 + c16;              /* global col */
    if (col > NC * PP - 1) col = NC * PP - 1;      /* replicate last col: max-invariant */
    int srow = col;                                /* [c][196] concat == global col */
    const float* sp = sup + (size_t)srow * DD + kk * 32 + quad * 8;
    float inv = sinv[srow];
    alignas(16) __hip_bfloat16 hb[8];
    #pragma unroll
    for (int e = 0; e < 8; ++e) hb[e] = __float2bfloat16(sp[e] * inv);
    *(uint4*)((char*)snw + (size_t)s * 16) = *(const uint4*)hb;
}

/* ---- main: one block per 32-row strip; A(query) staged in LDS fragment order;
        waves stream B(support) from L2, depth-3 pipeline, cross-tile prefetch,
        NO barriers in the main loop. SWAPPED MFMA OPERANDS: D = B_sup * A_qry,
        so output rows = support-cols -> col-max is 15 in-reg fmax + 2 shuffles
        (R2 lesson: the 4-deep x16 shuffle epilogue was a per-wave serial stall
        that 2 blocks/CU could not hide). 32-row blocks cut LDS 50.7->25 KB for
        5-6 blocks/CU of latency hiding; B L2 traffic doubles (27 TB/s @90us,
        under the 34.5 ceiling). ---- */
__global__ __launch_bounds__(256, 4) void k_gemm_max(const float* __restrict__ q,
                                                     const __hip_bfloat16* __restrict__ snw,
                                                     float* __restrict__ rowmaxg) {
    /* As fragment order: [kk 12][rt 2][lane 64][8 bf16] = 24576 B */
    __shared__ __hip_bfloat16 As[12 * 2 * 64 * 8];
    __shared__ unsigned rmax[BR * NC];
    __shared__ float rss[BR];

    const int tid  = threadIdx.x;
    const int row0 = blockIdx.x * BR;
    const int lane = tid & 63;
    const int wav  = tid >> 6;

    for (int i = tid; i < BR * NC; i += 256) rmax[i] = ENC_NEG_INF;

    /* ---- A staging: fp32 -> bf16 -> LDS fragment slots; fused row sumsq.
            Thread (arow=tid>>3, ch=asub+8i): kk=ch>>2, quad=ch&3,
            slot lane = quad*16 + (arow&15), rt = arow>>4.
            Non-temporal: query must not evict B from L2. */
    {
        const int arow = tid >> 3;                 /* 0..31 */
        const int asub = tid & 7;                  /* 0..7  */
        const int rt   = arow >> 4, c16 = arow & 15;
        const float* src = q + (size_t)(row0 + arow) * DD;
        float ss = 0.f;
        #pragma unroll
        for (int i = 0; i < 6; ++i) {
            int ch = asub + i * 8;                 /* 0..47 */
            const floatx4* p = (const floatx4*)(src + ch * 8);
            floatx4 x0 = __builtin_nontemporal_load(p);
            floatx4 x1 = __builtin_nontemporal_load(p + 1);
            ss += x0.x*x0.x + x0.y*x0.y + x0.z*x0.z + x0.w*x0.w
                + x1.x*x1.x + x1.y*x1.y + x1.z*x1.z + x1.w*x1.w;
            alignas(16) __hip_bfloat16 hb[8];
            hb[0] = __float2bfloat16(x0.x); hb[1] = __float2bfloat16(x0.y);
            hb[2] = __float2bfloat16(x0.z); hb[3] = __float2bfloat16(x0.w);
            hb[4] = __float2bfloat16(x1.x); hb[5] = __float2bfloat16(x1.y);
            hb[6] = __float2bfloat16(x1.z); hb[7] = __float2bfloat16(x1.w);
            int kk = ch >> 2, quad = ch & 3;
            *(uint4*)&As[((kk * 2 + rt) * 64 + quad * 16 + c16) * 8] = *(const uint4*)hb;
        }
        ss += __shfl_xor(ss, 1, 64);
        ss += __shfl_xor(ss, 2, 64);
        ss += __shfl_xor(ss, 4, 64);
        if (asub == 0) rss[arow] = ss;
    }

    /* B preload (kk 0..2 of this wave's first tile) overlaps the barrier */
    const char* bbase = (const char*)snw + (size_t)wav * TILE_BYTES + (size_t)lane * 16;
    short8 b0[4], b1[4], b2[4], a[2];
    #pragma unroll
    for (int ct = 0; ct < 4; ++ct) b0[ct] = ((const short8*)(bbase + 0 * KSTEP_BYTES))[ct * 64];
    #pragma unroll
    for (int ct = 0; ct < 4; ++ct) b1[ct] = ((const short8*)(bbase + 1 * KSTEP_BYTES))[ct * 64];
    #pragma unroll
    for (int ct = 0; ct < 4; ++ct) b2[ct] = ((const short8*)(bbase + 2 * KSTEP_BYTES))[ct * 64];

    __syncthreads();                            /* the ONLY barrier before the epilogue */

    #define LOAD_NEXT(buf, step)                                                     \
        do {                                                                         \
            int nk = kk + 3 + (step);                                                \
            if (nk < 12) {                                                           \
                _Pragma("unroll")                                                    \
                for (int ct = 0; ct < 4; ++ct)                                       \
                    buf[ct] = ((const short8*)(bbase + nk * KSTEP_BYTES))[ct * 64];  \
            } else if (g + 4 < NTILES) {                                             \
                _Pragma("unroll")                                                    \
                for (int ct = 0; ct < 4; ++ct)                                       \
                    buf[ct] = ((const short8*)(bbase + 4 * TILE_BYTES +              \
                                               (nk - 12) * KSTEP_BYTES))[ct * 64];   \
            }                                                                        \
        } while (0)

    /* swapped operands: a_frag = B(support cols -> D rows), b_frag = A(query rows -> D cols) */
    #define MFMA_STEP(buf, kkoff)                                                    \
        do {                                                                         \
            _Pragma("unroll")                                                        \
            for (int rt = 0; rt < 2; ++rt)                                           \
                a[rt] = *(const short8*)&As[(((kk + (kkoff)) * 2 + rt) * 64 + lane) * 8]; \
            _Pragma("unroll")                                                        \
            for (int ct = 0; ct < 4; ++ct)                                           \
                _Pragma("unroll")                                                    \
                for (int rt = 0; rt < 2; ++rt)                                       \
                    acc[ct][rt] = __builtin_amdgcn_mfma_f32_16x16x32_bf16(           \
                        buf[ct], a[rt], acc[ct][rt], 0, 0, 0);                       \
        } while (0)

    #pragma unroll 1
    for (int g = wav; g < NTILES; g += 4) {
        floatx4 acc[4][2];
        #pragma unroll
        for (int i = 0; i < 4; ++i)
            #pragma unroll
            for (int j = 0; j < 2; ++j) acc[i][j] = (floatx4){0.f, 0.f, 0.f, 0.f};

        #pragma unroll 1
        for (int kk = 0; kk < 12; kk += 3) {
            MFMA_STEP(b0, 0); LOAD_NEXT(b0, 0);
            MFMA_STEP(b1, 1); LOAD_NEXT(b1, 1);
            MFMA_STEP(b2, 2); LOAD_NEXT(b2, 2);
        }

        /* ---- epilogue: per-class col-max. Swapped C layout:
                D row (support col) = g*64 + ct*16 + (lane>>4)*4 + reg,
                D col (query row)   = rt*16 + (lane&15).
                Max over support cols = 15 in-reg fmax + 2 shuffles per rt.
                Boundary tiles (g=3,6,9,12; one per wave) split once at chi*196.
                Overlaps the already-issued next-tile B loads. ---- */
        {
            const int colbase = g * 64;
            int ce = colbase + 63; if (ce > NC * PP - 1) ce = NC * PP - 1;
            const int clo = cls_of(colbase), chi = cls_of(ce);
            const int quad = lane >> 4;
            if (clo == chi) {                      /* common case: single class */
                #pragma unroll
                for (int rt = 0; rt < 2; ++rt) {
                    float mx = acc[0][rt][0];
                    #pragma unroll
                    for (int ct = 0; ct < 4; ++ct)
                        #pragma unroll
                        for (int reg = 0; reg < 4; ++reg)
                            if (ct | reg) mx = fmaxf(mx, acc[ct][rt][reg]);
                    mx = fmaxf(mx, __shfl_xor(mx, 16, 64));
                    mx = fmaxf(mx, __shfl_xor(mx, 32, 64));
                    if (lane < 16) atomicMax(&rmax[(rt * 16 + lane) * NC + clo], enc_f(mx));
                }
            } else {                               /* one boundary tile per wave */
                const int bnd = chi * PP;
                #pragma unroll
                for (int rt = 0; rt < 2; ++rt) {
                    float mlo = -INFINITY, mhi = -INFINITY;
                    #pragma unroll
                    for (int ct = 0; ct < 4; ++ct)
                        #pragma unroll
                        for (int reg = 0; reg < 4; ++reg) {
                            int scol = colbase + ct * 16 + quad * 4 + reg;
                            if (scol >= bnd) mhi = fmaxf(mhi, acc[ct][rt][reg]);
                            else             mlo = fmaxf(mlo, acc[ct][rt][reg]);
                        }
                    mlo = fmaxf(mlo, __shfl_xor(mlo, 16, 64));
                    mlo = fmaxf(mlo, __shfl_xor(mlo, 32, 64));
                    mhi = fmaxf(mhi, __shfl_xor(mhi, 16, 64));
                    mhi = fmaxf(mhi, __shfl_xor(mhi, 32, 64));
                    if (lane < 16) {
                        atomicMax(&rmax[(rt * 16 + lane) * NC + clo], enc_f(mlo));
                        atomicMax(&rmax[(rt * 16 + lane) * NC + chi], enc_f(mhi));
                    }
                }
            }
        }
        bbase += 4 * TILE_BYTES;
    }

    __syncthreads();
    /* rowmaxg layout [c][row] -> coalesced stores here, coalesced loads in k_top6 */
    for (int i = tid; i < BR * NC; i += 256) {
        int c = i >> 5, row = i & 31;
        float inv = 1.0f / fmaxf(sqrtf(rss[row]), EPSN);
        __builtin_nontemporal_store(dec_f(rmax[row * NC + c]) * inv,
                                    &rowmaxg[(size_t)c * ROWS + row0 + row]);
    }
}

/* ---- top-6 sum per (m, c): one wave each ---- */
__global__ __launch_bounds__(256) void k_top6(const float* __restrict__ rowmaxg,
                                              const float* __restrict__ scale,
                                              const float* __restrict__ bias,
                                              float* __restrict__ out) {
    int wav = threadIdx.x >> 6, lane = threadIdx.x & 63;
    int pair = blockIdx.x * 4 + wav;
    if (pair >= MM * NC) return;
    int m = pair / NC, c = pair % NC;
    size_t base = (size_t)c * ROWS + (size_t)m * PP;
    float v[4];
    #pragma unroll
    for (int i = 0; i < 4; ++i) {
        int p = lane + i * 64;
        v[i] = (p < PP) ? rowmaxg[base + p] : -INFINITY;
    }
    float sum = 0.f;
    for (int t = 0; t < 6; ++t) {
        float bv = v[0]; int bi = 0;
        #pragma unroll
        for (int i = 1; i < 4; ++i) { if (v[i] > bv) { bv = v[i]; bi = i; } }
        int gid = bi * 64 + lane;
        #pragma unroll
        for (int off = 1; off < 64; off <<= 1) {
            float ov = __shfl_xor(bv, off, 64);
            int og  = __shfl_xor(gid, off, 64);
            if (ov > bv || (ov == bv && og < gid)) { bv = ov; gid = og; }
        }
        sum += bv;
        if ((gid & 63) == lane) v[gid >> 6] = -INFINITY;  /* kill exactly one */
    }
    if (lane == 0) out[pair] = scale[0] * (sum + bias[0]);
}

extern "C" void kernel_launch(void* const* d_in, const int* in_sizes, int n_in,
                              void* d_out, int out_size, void* d_ws, size_t ws_size,
                              hipStream_t stream) {
    const float* support = (const float*)d_in[0];
    const float* query   = (const float*)d_in[1];
    const float* scale   = (const float*)d_in[2];
    const float* bias    = (const float*)d_in[3];
    float* out = (float*)d_out;

    char* ws = (char*)d_ws;
    __hip_bfloat16* snw = (__hip_bfloat16*)ws;             /* 16*49152 = 786432 B */
    float* sinv         = (float*)(ws + 786432);           /* 980*4 -> pad to 4096 */
    float* rowmaxg      = (float*)(ws + 786432 + 4096);    /* 5*100352*4 = 2007040 */

    hipLaunchKernelGGL(k_norm0,   dim3(245),  dim3(256), 0, stream, support, sinv);
    hipLaunchKernelGGL(k_swz,     dim3(192),  dim3(256), 0, stream, support, sinv, snw);
    hipLaunchKernelGGL(k_gemm_max,dim3(NRB),  dim3(256), 0, stream, query, snw, rowmaxg);
    hipLaunchKernelGGL(k_top6,    dim3(640),  dim3(256), 0, stream, rowmaxg, scale, bias, out);
}